// Round 1
// baseline (41.294 us; speedup 1.0000x reference)
//
#include <hip/hip_runtime.h>

// Routing: out[row] = x[row] if expert 0 is in top-2 of x[row][0..7] else 0.
// top_k tie-break favors lower index, so expert 0 wins ties:
// condition == (count of j in 1..7 with x[j] > x[0]) <= 1.
__global__ void __launch_bounds__(256) route_e0_kernel(
    const float4* __restrict__ x, float4* __restrict__ out, int nrows) {
    int idx = blockIdx.x * blockDim.x + threadIdx.x;
    int stride = gridDim.x * blockDim.x;
    for (int r = idx; r < nrows; r += stride) {
        float4 a = x[2 * r];       // experts 0..3
        float4 b = x[2 * r + 1];   // experts 4..7
        float x0 = a.x;
        int cnt = (a.y > x0) + (a.z > x0) + (a.w > x0)
                + (b.x > x0) + (b.y > x0) + (b.z > x0) + (b.w > x0);
        if (cnt > 1) {
            a = make_float4(0.f, 0.f, 0.f, 0.f);
            b = make_float4(0.f, 0.f, 0.f, 0.f);
        }
        out[2 * r]     = a;
        out[2 * r + 1] = b;
    }
}

extern "C" void kernel_launch(void* const* d_in, const int* in_sizes, int n_in,
                              void* d_out, int out_size, void* d_ws, size_t ws_size,
                              hipStream_t stream) {
    const float4* x = (const float4*)d_in[0];
    float4* out = (float4*)d_out;
    int nrows = in_sizes[0] / 8;  // 8 experts per row

    const int block = 256;
    int grid = (nrows + block - 1) / block;
    if (grid > 2048) grid = 2048;  // grid-stride the rest (memory-bound)
    route_e0_kernel<<<grid, block, 0, stream>>>(x, out, nrows);
}